// Round 8
// baseline (160.686 us; speedup 1.0000x reference)
//
#include <hip/hip_runtime.h>
#include <math.h>

// B=1, S=4096, H=8, DH=40, D=320, fp32 in/out.  FOUR kernels (R8):
// prep:     convert x + Wq/Wk/Wv/Wo to bf16 once (pq re-reads x 15x, W 64x;
//           bf16 halves that traffic and deletes per-tile cvt VALU); zero Cnt.
// proj_qkv: 64x64-tile MFMA GEMM, BK=64, dbuf LDS (1 barrier/iter, prefetch
//           dist 2), bf16 sources -> Qp/Kp [h][s][48] (Q pre-scaled; pad
//           carries -32), Vt [h][40][4096].
// attn:     MFMA flash (R6 body, untouched core). ks=2 splits, 32 iters.
//           R8: split-K fixup epilogue -- second finisher of each (h,qt)
//           combines both partials -> Xo (replaces combine kernel).
// proj_out: 64x64-tile MFMA GEMM + bias (bf16 Wo) -> out fp32.
// NOTE: harness re-poison (~41us fillBuffer of 268MB ws) is inside the timed
// window and fixed; optimizable budget is ~78us.
// R7 lesson: hipLaunchCooperativeKernel silently no-ops under graph capture
// (output stayed zero) -- plain launches only.

#define NS 4096
#define ND 320
#define SCALE2 0.2281101152f      // log2(e)/sqrt(40)
#define HS48 196608               // 4096*48 per head
#define VTH 163840                // 40*4096 per head
#define XN 1310720
#define WN 102400                 // 320*320

// attn LDS geometry (shorts)
#define KSTR 56                   // K row stride: 112B = 7 chunks (odd -> cf)
#define VSTR 72                   // V row stride: 144B = 9 chunks (odd -> cf)
#define VB   3584                 // 64*KSTR
#define BUF  7040                 // VB + 48*VSTR

typedef __attribute__((ext_vector_type(8))) short bf16x8;
typedef __attribute__((ext_vector_type(16))) float f32x16;

static __device__ __forceinline__ unsigned short f2bru(float f) {
  return (unsigned short)((__builtin_bit_cast(unsigned int, f) + 0x8000u) >> 16);
}
static __device__ __forceinline__ unsigned int pk2ru(float a, float b) {
  unsigned int ua = __builtin_bit_cast(unsigned int, a) + 0x8000u;
  unsigned int ub = __builtin_bit_cast(unsigned int, b) + 0x8000u;
  return __builtin_amdgcn_perm(ub, ua, 0x07060302u);
}
static __device__ __forceinline__ unsigned int pk2t(float a, float b) {
  return __builtin_amdgcn_perm(__builtin_bit_cast(unsigned int, b),
                               __builtin_bit_cast(unsigned int, a), 0x07060302u);
}
static __device__ __forceinline__ float fexp2(float x) {
  return __builtin_amdgcn_exp2f(x);
}
// 16B-aligned LDS ops: single ds_read_b128 / ds_write_b128
static __device__ __forceinline__ bf16x8 ld8a(const unsigned short* p) {
  return __builtin_bit_cast(bf16x8, *(const uint4*)p);
}
static __device__ __forceinline__ void st16a(unsigned short* p, uint4 v) {
  *(uint4*)p = v;
}
static __device__ __forceinline__ uint4 ld16u(const unsigned short* p) {
  uint2 a = *(const uint2*)p, b = *(const uint2*)(p + 4);
  return make_uint4(a.x, a.y, b.x, b.y);
}
static __device__ __forceinline__ void st16(unsigned short* p, uint4 v) {
  *(uint2*)p = make_uint2(v.x, v.y);
  *(uint2*)(p + 4) = make_uint2(v.z, v.w);
}
// sigma: phys key (0..31) -> MFMA m-row so QK C/D regs land in PV A order
static __device__ __forceinline__ int sig32(int q) {
  int s = q >> 4, h2 = (q >> 3) & 1, j = q & 7;
  return (s << 4) | ((j >> 2) << 3) | (h2 << 2) | (j & 3);
}

// ---------------------------------------------------------------------------
// Kernel 0: convert x (XN) + 4 weight matrices (WN each) fp32 -> bf16.
// grid 840 x 256, 8 elems/thread. Block 0 also zeroes the 256 fixup counters.
// ---------------------------------------------------------------------------
__global__ __launch_bounds__(256) void prep_kernel(
    const float* __restrict__ x, const float* __restrict__ Wq,
    const float* __restrict__ Wk, const float* __restrict__ Wv,
    const float* __restrict__ Wo, unsigned short* __restrict__ Xb,
    unsigned short* __restrict__ Wqb, unsigned short* __restrict__ Wkb,
    unsigned short* __restrict__ Wvb, unsigned short* __restrict__ Wob,
    int* __restrict__ Cnt) {
  int idx = (blockIdx.x * 256 + threadIdx.x) * 8;
  const float* src;
  unsigned short* dst;
  int off;
  if (idx < XN) {
    src = x; dst = Xb; off = idx;
  } else {
    int r = idx - XN;
    int wsel = r / WN;
    off = r - wsel * WN;
    src = (wsel == 0) ? Wq : (wsel == 1) ? Wk : (wsel == 2) ? Wv : Wo;
    dst = (wsel == 0) ? Wqb : (wsel == 1) ? Wkb : (wsel == 2) ? Wvb : Wob;
  }
  float4 v0 = *(const float4*)(src + off), v1 = *(const float4*)(src + off + 4);
  *(uint4*)(dst + off) = make_uint4(pk2ru(v0.x, v0.y), pk2ru(v0.z, v0.w),
                                    pk2ru(v1.x, v1.y), pk2ru(v1.z, v1.w));
  if (blockIdx.x == 0) Cnt[threadIdx.x] = 0;
}

// ---------------------------------------------------------------------------
// Kernel 1: q/k/v = xb @ Wb^T (bf16 sources). 64x64 tile, BK=64, 5 K-iters,
// dbuf LDS (1 barrier/iter, prefetch dist 2). grid (64, 15): z = y/5,
// bnn = (y%5)*64. 4 waves in 2x2 layout. A/B stride 88 shorts (cf b128).
// ---------------------------------------------------------------------------
__global__ __launch_bounds__(256) void proj_qkv_kernel(
    const unsigned short* __restrict__ Xb, const unsigned short* __restrict__ Wqb,
    const unsigned short* __restrict__ Wkb, const unsigned short* __restrict__ Wvb,
    unsigned short* __restrict__ Qp, unsigned short* __restrict__ Kp,
    unsigned short* __restrict__ Vt) {
  const int zi = blockIdx.y;
  const int z = zi / 5;
  const int bnn = (zi - z * 5) * 64;
  const unsigned short* W = (z == 0) ? Wqb : (z == 1) ? Wkb : Wvb;
  __shared__ __align__(16) unsigned short As[2][64 * 88];
  __shared__ __align__(16) unsigned short Bs[2][64 * 88];
  const int t = threadIdx.x;
  const int w = t >> 6, l = t & 63, l31 = l & 31, hi = l >> 5;
  const int bm = blockIdx.x * 64;
  const int m0 = (w >> 1) * 32, n0 = (w & 1) * 32;
  f32x16 acc = {0,0,0,0,0,0,0,0,0,0,0,0,0,0,0,0};
  const int afo = (m0 + l31) * 88 + hi * 8;
  const int bfo = (n0 + l31) * 88 + hi * 8;
  const int row0 = t >> 3, row1 = row0 + 32, kc = (t & 7) << 3;
  const unsigned short* xb = Xb + (bm + row0) * ND + kc;
  const unsigned short* xb1 = Xb + (bm + row1) * ND + kc;
  const unsigned short* Wb = W + (bnn + row0) * ND + kc;
  const unsigned short* Wb1 = W + (bnn + row1) * ND + kc;
  const int so0 = row0 * 88 + kc, so1 = row1 * 88 + kc;

  uint4 a0v, a1v, b0v, b1v;
#define PQ_LOAD(K)                              \
  do {                                          \
    a0v = *(const uint4*)(xb + (K));            \
    a1v = *(const uint4*)(xb1 + (K));           \
    b0v = *(const uint4*)(Wb + (K));            \
    b1v = *(const uint4*)(Wb1 + (K));           \
  } while (0)
#define PQ_STORE(BUFI)                          \
  do {                                          \
    st16a(&As[BUFI][so0], a0v);                 \
    st16a(&As[BUFI][so1], a1v);                 \
    st16a(&Bs[BUFI][so0], b0v);                 \
    st16a(&Bs[BUFI][so1], b1v);                 \
  } while (0)

  PQ_LOAD(0);
  PQ_STORE(0);
  PQ_LOAD(64);
  __syncthreads();
#pragma unroll
  for (int it = 0; it < 5; ++it) {
    const int cur = it & 1, nxt = cur ^ 1;
    if (it < 4) PQ_STORE(nxt);                 // stage tile it+1
    {                                          // prefetch tile it+2 (clamped)
      int kp = (it + 2) * 64;
      if (kp >= ND) kp = 0;                    // wasted-but-safe reload
      PQ_LOAD(kp);
    }
#pragma unroll
    for (int kk = 0; kk < 4; kk++) {
      acc = __builtin_amdgcn_mfma_f32_32x32x16_bf16(
          ld8a(&As[cur][afo + kk * 16]), ld8a(&Bs[cur][bfo + kk * 16]), acc, 0, 0, 0);
    }
    __syncthreads();
  }
#undef PQ_LOAD
#undef PQ_STORE

  unsigned short* Tile = &As[0][0];            // compute done; reuse as Tile
  if (z < 2) {
    // ---- Q/K epilogue: Tile [64 rows][64 cols] stride 68 ----
    unsigned short* Y = (z == 0) ? Qp : Kp;
    const float sc = (z == 0) ? SCALE2 : 1.0f;
    const unsigned int padw = (z == 0) ? 0xC200u : 0x3F80u;  // -32.0 : 1.0
#pragma unroll
    for (int r2 = 0; r2 < 16; r2++) {
      int lr = m0 + (r2 & 3) + 8 * (r2 >> 2) + 4 * hi;
      Tile[lr * 68 + n0 + l31] = f2bru(acc[r2] * sc);
    }
    __syncthreads();
#pragma unroll
    for (int i = 0; i < 2; i++) {              // 64 rows x 8 chunks
      int c = t + i * 256;
      int row = c >> 3, ch = c & 7;
      int j = bnn + ch * 8;
      int h = j / 40, dh = j - h * 40;
      uint4 v = ld16u(Tile + row * 68 + ch * 8);
      st16(Y + h * HS48 + (bm + row) * 48 + dh, v);
      if (dh == 0)
        st16(Y + h * HS48 + (bm + row) * 48 + 40, make_uint4(padw, 0u, 0u, 0u));
    }
  } else {
    // ---- V epilogue: transposed Tile [64 j][64 s] stride 68 ----
#pragma unroll
    for (int r2 = 0; r2 < 16; r2++) {
      int lr = m0 + (r2 & 3) + 8 * (r2 >> 2) + 4 * hi;
      Tile[(n0 + l31) * 68 + lr] = f2bru(acc[r2]);
    }
    __syncthreads();
#pragma unroll
    for (int i = 0; i < 2; i++) {              // 64 j-rows x 8 s-chunks
      int c = t + i * 256;
      int row = c >> 3, ch = c & 7;
      int j = bnn + row;
      int h = j / 40, dd = j - h * 40;
      uint4 v = ld16u(Tile + row * 68 + ch * 8);
      st16(Vt + h * VTH + dd * NS + bm + ch * 8, v);
    }
  }
}

// ---------------------------------------------------------------------------
// Kernel 2: MFMA flash attention. grid 512 x 256. h=b&7 XCD swizzle,
// ks=2 key-splits of 2048 keys, 32 iters of 64-key tiles, 128 q-rows/block.
// Double-buffered LDS (BUF shorts/buffer), 1 barrier/iter, prefetch-2,
// 16B-aligned odd-stride (conflict-free b128).
// R8 epilogue: split-K fixup -- second finisher of (h,qt) combines both
// partials (Op,Lp) into normalized Xo (device-scope fences for cross-XCD).
// ---------------------------------------------------------------------------
__global__ __launch_bounds__(256, 4) void attn_kernel(
    const unsigned short* __restrict__ Qp, const unsigned short* __restrict__ Kp,
    const unsigned short* __restrict__ Vt, unsigned short* __restrict__ Op,
    float* __restrict__ Lp, unsigned short* __restrict__ Xo,
    int* __restrict__ Cnt) {
  const int b = blockIdx.x;
  const int h = b & 7, ks = (b >> 3) & 1, qt = b >> 4;   // qt in 0..31
  const int t = threadIdx.x;
  const int w = t >> 6, l = t & 63, l31 = l & 31, hi = l >> 5;
  __shared__ __align__(16) unsigned short Lds[2 * BUF];
  __shared__ int smFlag;
  // V rows 40..47 in BOTH buffers: row 40 = ones (cols 0..63), rest zero.
  for (int i = t; i < 576; i += 256) {
    int bsel = (i >= 288) ? 1 : 0;
    int ui = i - bsel * 288;
    int rr = ui / 36, cc = ui - rr * 36;
    ((unsigned int*)Lds)[bsel * (BUF / 2) + (VB / 2) + (40 + rr) * 36 + cc] =
        (rr == 0 && cc < 32) ? 0x3F803F80u : 0u;
  }

  const int kbase = ks * 2048;
  const int qbase = qt * 128 + w * 32;
  const unsigned short* qp = Qp + h * HS48 + (qbase + l31) * 48 + hi * 8;
  bf16x8 qf0 = *(const bf16x8*)qp;
  bf16x8 qf1 = *(const bf16x8*)(qp + 16);
  bf16x8 qf2 = *(const bf16x8*)(qp + 32);   // includes {-32,0..} pad

  const f32x16 Z = {0,0,0,0,0,0,0,0,0,0,0,0,0,0,0,0};  // hoisted zero-C
  f32x16 oa0 = Z, oa1 = Z;

  // unified staging map: chunk ids 0..383 = K (kr=id/6, kc=id%6),
  // ids 384..703 = V (vr=(id-384)>>3 in 0..39, vc=(id-384)&7).
  const int id1 = t + 256;
  const bool has2 = (t < 192);
  const int kr0 = t / 6, kc0 = t - kr0 * 6;
  const unsigned short* g0 = Kp + h * HS48 + (kbase + kr0) * 48 + kc0 * 8;
  const int w0 = ((kr0 & 32) | sig32(kr0 & 31)) * KSTR + kc0 * 8;
  const unsigned short* g1;
  int w1, inc1;
  if (id1 < 384) {
    int kr = id1 / 6, kc = id1 - kr * 6;
    g1 = Kp + h * HS48 + (kbase + kr) * 48 + kc * 8;
    w1 = ((kr & 32) | sig32(kr & 31)) * KSTR + kc * 8;
    inc1 = 64 * 48;
  } else {
    int vid = id1 - 384, vr = vid >> 3, vc = vid & 7;
    g1 = Vt + h * VTH + vr * NS + kbase + vc * 8;
    w1 = VB + vr * VSTR + vc * 8;
    inc1 = 64;
  }
  const int vid2 = t + 128;                   // id2 - 384, valid for t<192
  const int vr2 = vid2 >> 3, vc2 = vid2 & 7;  // rows 16..39
  const unsigned short* g2 = Vt + h * VTH + vr2 * NS + kbase + vc2 * 8;
  const int w2 = VB + vr2 * VSTR + vc2 * 8;

  const int rk  = l31 * KSTR + hi * 8;                 // kf0 (+32*KSTR = kf1)
  const int rv0 = VB + l31 * VSTR + hi * 8;
  const int rv1 = VB + (32 + (l31 & 15)) * VSTR + hi * 8;

  // prologue: tile 0 -> buf0, tile 1 -> regs
  uint4 r0 = *(const uint4*)g0; g0 += 3072;
  uint4 r1 = *(const uint4*)g1; g1 += inc1;
  uint4 r2{};
  if (has2) { r2 = *(const uint4*)g2; g2 += 64; }
  st16a(Lds + w0, r0);
  st16a(Lds + w1, r1);
  if (has2) st16a(Lds + w2, r2);
  r0 = *(const uint4*)g0; g0 += 3072;
  r1 = *(const uint4*)g1; g1 += inc1;
  if (has2) { r2 = *(const uint4*)g2; g2 += 64; }
  __syncthreads();

  for (int it = 0; it < 32; ++it) {
    const int bo = (it & 1) ? BUF : 0;
    const int bn = BUF - bo;
    // stage tile it+1 into the other buffer; issue loads for tile it+2.
    st16a(Lds + bn + w0, r0);
    st16a(Lds + bn + w1, r1);
    if (has2) st16a(Lds + bn + w2, r2);
    r0 = *(const uint4*)g0; g0 += 3072;
    r1 = *(const uint4*)g1; g1 += inc1;
    if (has2) { r2 = *(const uint4*)g2; g2 += 64; }

    const unsigned short* kf0 = Lds + bo + rk;
    const unsigned short* kf1 = kf0 + 32 * KSTR;
    const unsigned short* vf0 = Lds + bo + rv0;
    const unsigned short* vf1 = Lds + bo + rv1;

    __builtin_amdgcn_s_setprio(1);
    {  // m-tile 0: phys keys 0..31 (sigma rows)
      f32x16 s0 = __builtin_amdgcn_mfma_f32_32x32x16_bf16(ld8a(kf0), qf0, Z, 0, 0, 0);
      s0 = __builtin_amdgcn_mfma_f32_32x32x16_bf16(ld8a(kf0 + 16), qf1, s0, 0, 0, 0);
      s0 = __builtin_amdgcn_mfma_f32_32x32x16_bf16(ld8a(kf0 + 32), qf2, s0, 0, 0, 0);
      unsigned int pw[8];
#pragma unroll
      for (int i = 0; i < 8; i++)
        pw[i] = pk2t(fexp2(s0[2 * i]), fexp2(s0[2 * i + 1]));
      bf16x8 pf0 = __builtin_bit_cast(bf16x8, make_uint4(pw[0], pw[1], pw[2], pw[3]));
      bf16x8 pf1 = __builtin_bit_cast(bf16x8, make_uint4(pw[4], pw[5], pw[6], pw[7]));
      oa0 = __builtin_amdgcn_mfma_f32_32x32x16_bf16(pf0, ld8a(vf0), oa0, 0, 0, 0);
      oa1 = __builtin_amdgcn_mfma_f32_32x32x16_bf16(pf0, ld8a(vf1), oa1, 0, 0, 0);
      oa0 = __builtin_amdgcn_mfma_f32_32x32x16_bf16(pf1, ld8a(vf0 + 16), oa0, 0, 0, 0);
      oa1 = __builtin_amdgcn_mfma_f32_32x32x16_bf16(pf1, ld8a(vf1 + 16), oa1, 0, 0, 0);
    }
    {  // m-tile 1: phys keys 32..63
      f32x16 s1 = __builtin_amdgcn_mfma_f32_32x32x16_bf16(ld8a(kf1), qf0, Z, 0, 0, 0);
      s1 = __builtin_amdgcn_mfma_f32_32x32x16_bf16(ld8a(kf1 + 16), qf1, s1, 0, 0, 0);
      s1 = __builtin_amdgcn_mfma_f32_32x32x16_bf16(ld8a(kf1 + 32), qf2, s1, 0, 0, 0);
      unsigned int pw[8];
#pragma unroll
      for (int i = 0; i < 8; i++)
        pw[i] = pk2t(fexp2(s1[2 * i]), fexp2(s1[2 * i + 1]));
      bf16x8 pf2 = __builtin_bit_cast(bf16x8, make_uint4(pw[0], pw[1], pw[2], pw[3]));
      bf16x8 pf3 = __builtin_bit_cast(bf16x8, make_uint4(pw[4], pw[5], pw[6], pw[7]));
      oa0 = __builtin_amdgcn_mfma_f32_32x32x16_bf16(pf2, ld8a(vf0 + 32), oa0, 0, 0, 0);
      oa1 = __builtin_amdgcn_mfma_f32_32x32x16_bf16(pf2, ld8a(vf1 + 32), oa1, 0, 0, 0);
      oa0 = __builtin_amdgcn_mfma_f32_32x32x16_bf16(pf3, ld8a(vf0 + 48), oa0, 0, 0, 0);
      oa1 = __builtin_amdgcn_mfma_f32_32x32x16_bf16(pf3, ld8a(vf1 + 48), oa1, 0, 0, 0);
    }
    __builtin_amdgcn_s_setprio(0);
    __syncthreads();
  }

  unsigned short* opb = Op + ks * XN + h * 163840;
  float* lpb = Lp + ks * 32768 + h * NS;
#pragma unroll
  for (int r2i = 0; r2i < 16; r2i++) {
    int qr = qbase + (r2i & 3) + 8 * (r2i >> 2) + 4 * hi;
    opb[qr * 40 + l31] = f2bru(oa0[r2i]);
    if (l31 < 8) opb[qr * 40 + 32 + l31] = f2bru(oa1[r2i]);
    if (l31 == 8) lpb[qr] = oa1[r2i];   // l = Sum(p) via ones-row at dh=40
  }

  // ---- split-K fixup: second finisher of (h,qt) combines both partials ----
  __syncthreads();                 // all partial stores drained (vmcnt 0)
  if (t == 0) {
    __threadfence();               // release: make stores agent-visible
    smFlag = atomicAdd(&Cnt[h * 32 + qt], 1);
  }
  __syncthreads();
  if (smFlag == 0) return;         // first finisher exits
  __threadfence();                 // acquire: see partner block's partial
  const int base = h * 163840 + qt * 5120;   // 128 rows x 40 dh (shorts)
  for (int i = t; i < 2560; i += 256) {
    int i2 = i * 2;
    int r = i2 / 40;
    int dh = i2 - r * 40;
    int s = qt * 128 + r;
    float lsum = Lp[h * NS + s] + Lp[32768 + h * NS + s];
    float inv = 1.0f / lsum;
    unsigned int u0 = *(const unsigned int*)(Op + base + i2);
    unsigned int u1 = *(const unsigned int*)(Op + XN + base + i2);
    float a0 = __builtin_bit_cast(float, u0 << 16) +
               __builtin_bit_cast(float, u1 << 16);
    float a1 = __builtin_bit_cast(float, u0 & 0xFFFF0000u) +
               __builtin_bit_cast(float, u1 & 0xFFFF0000u);
    *(unsigned int*)(Xo + s * ND + h * 40 + dh) = pk2ru(a0 * inv, a1 * inv);
  }
}

// ---------------------------------------------------------------------------
// Kernel 3: out = Xo @ Wob^T + bo (bf16 sources). 64x64 tile, BK=64, 5
// iters, grid (64, 5) = 320 blocks. 4 waves in 2x2 layout. A/B stride 88.
// ---------------------------------------------------------------------------
__global__ __launch_bounds__(256) void proj_out_kernel(
    const unsigned short* __restrict__ Xo, const unsigned short* __restrict__ Wob,
    const float* __restrict__ bo, float* __restrict__ out) {
  __shared__ __align__(16) unsigned short As[64 * 88];
  __shared__ __align__(16) unsigned short Bs[64 * 88];
  const int t = threadIdx.x;
  const int w = t >> 6, l = t & 63, l31 = l & 31, hi = l >> 5;
  const int bm = blockIdx.x * 64;
  const int bnn = blockIdx.y * 64;
  const int m0 = (w >> 1) * 32, n0 = (w & 1) * 32;
  f32x16 acc = {0,0,0,0,0,0,0,0,0,0,0,0,0,0,0,0};
  const unsigned short* af = As + (m0 + l31) * 88 + hi * 8;
  const unsigned short* bf = Bs + (n0 + l31) * 88 + hi * 8;
  for (int k0 = 0; k0 < ND; k0 += 64) {
    __syncthreads();
#pragma unroll
    for (int i = 0; i < 2; i++) {            // A: 64 rows x 8 chunks, bf16 src
      int c = t + i * 256;
      int row = c >> 3, kc = (c & 7) << 3;
      uint4 v = *(const uint4*)(Xo + (bm + row) * ND + k0 + kc);
      st16a(As + row * 88 + kc, v);
    }
#pragma unroll
    for (int i = 0; i < 2; i++) {            // B: 64 rows x 8 chunks, bf16 src
      int c = t + i * 256;
      int row = c >> 3, kc = (c & 7) << 3;
      uint4 v = *(const uint4*)(Wob + (bnn + row) * ND + k0 + kc);
      st16a(Bs + row * 88 + kc, v);
    }
    __syncthreads();
#pragma unroll
    for (int ks = 0; ks < 4; ks++) {
      acc = __builtin_amdgcn_mfma_f32_32x32x16_bf16(
          ld8a(af + ks * 16), ld8a(bf + ks * 16), acc, 0, 0, 0);
    }
  }
  const int j = bnn + n0 + l31;
  const float bj = bo[j];
#pragma unroll
  for (int r2 = 0; r2 < 16; r2++) {
    int row = bm + m0 + (r2 & 3) + 8 * (r2 >> 2) + 4 * hi;
    out[row * ND + j] = acc[r2] + bj;
  }
}

extern "C" void kernel_launch(void* const* d_in, const int* in_sizes, int n_in,
                              void* d_out, int out_size, void* d_ws, size_t ws_size,
                              hipStream_t stream) {
  (void)in_sizes; (void)n_in; (void)out_size; (void)ws_size;
  const float* x  = (const float*)d_in[0];
  const float* Wq = (const float*)d_in[1];
  const float* Wk = (const float*)d_in[2];
  const float* Wv = (const float*)d_in[3];
  const float* Wo = (const float*)d_in[4];
  const float* bo = (const float*)d_in[5];
  float* out = (float*)d_out;

  unsigned short* Qp = (unsigned short*)d_ws;   // 8*HS48
  unsigned short* Kp = Qp + 8 * HS48;           // 8*HS48
  unsigned short* Vt = Kp + 8 * HS48;           // 8*VTH
  unsigned short* Xo = Vt + 8 * VTH;            // XN
  unsigned short* Op = Xo + XN;                 // 2*XN bf16 partials
  float* Lp = (float*)(Op + 2 * XN);            // 2*32768 fp32
  unsigned short* Xb = (unsigned short*)(Lp + 65536);   // XN bf16 x
  unsigned short* Wqb = Xb + XN;                // WN each, bf16 weights
  unsigned short* Wkb = Wqb + WN;
  unsigned short* Wvb = Wkb + WN;
  unsigned short* Wob = Wvb + WN;
  int* Cnt = (int*)(Wob + WN);                  // 256 fixup counters
  // ws use ~21 MB

  prep_kernel<<<dim3(840), 256, 0, stream>>>(x, Wq, Wk, Wv, Wo,
                                             Xb, Wqb, Wkb, Wvb, Wob, Cnt);
  proj_qkv_kernel<<<dim3(64, 15), 256, 0, stream>>>(Xb, Wqb, Wkb, Wvb,
                                                    Qp, Kp, Vt);
  attn_kernel<<<dim3(512), 256, 0, stream>>>(Qp, Kp, Vt, Op, Lp, Xo, Cnt);
  proj_out_kernel<<<dim3(64, 5), 256, 0, stream>>>(Xo, Wob, bo, out);
}

// Round 9
// 120.779 us; speedup vs baseline: 1.3304x; 1.3304x over previous
//
#include <hip/hip_runtime.h>
#include <math.h>

// B=1, S=4096, H=8, DH=40, D=320, fp32 in/out.  FIVE kernels (R9):
// prep:     convert x + Wq/Wk/Wv/Wo to bf16 once (pq re-reads x 15x, W 64x).
// proj_qkv: 64x64-tile MFMA GEMM, BK=64, dbuf LDS, bf16 sources ->
//           Qp/Kp [h][s][48] (Q pre-scaled; pad -32), Vt [h][40][4096].
// attn:     MFMA flash (R6 body, plain partial-store epilogue). ks=2, 32 it.
// combine:  sum 2 bf16 partials, normalize -> Xo; uint4, grid 640.
// proj_out: 64x64-tile MFMA GEMM + bias (bf16 Wo) -> out fp32.
// R8 lesson: __threadfence (device fence) during concurrent compute = L2
// invalidate storm across the XCD, +47us on attn. No cross-block fixups.
// R7 lesson: hipLaunchCooperativeKernel silently no-ops under graph capture.
// NOTE: harness re-poison (~41us fillBuffer of 268MB ws) is inside the timed
// window and fixed; optimizable budget is ~78us.

#define NS 4096
#define ND 320
#define SCALE2 0.2281101152f      // log2(e)/sqrt(40)
#define HS48 196608               // 4096*48 per head
#define VTH 163840                // 40*4096 per head
#define XN 1310720
#define WN 102400                 // 320*320

// attn LDS geometry (shorts)
#define KSTR 56                   // K row stride: 112B = 7 chunks (odd -> cf)
#define VSTR 72                   // V row stride: 144B = 9 chunks (odd -> cf)
#define VB   3584                 // 64*KSTR
#define BUF  7040                 // VB + 48*VSTR

typedef __attribute__((ext_vector_type(8))) short bf16x8;
typedef __attribute__((ext_vector_type(16))) float f32x16;

static __device__ __forceinline__ unsigned short f2bru(float f) {
  return (unsigned short)((__builtin_bit_cast(unsigned int, f) + 0x8000u) >> 16);
}
static __device__ __forceinline__ unsigned int pk2ru(float a, float b) {
  unsigned int ua = __builtin_bit_cast(unsigned int, a) + 0x8000u;
  unsigned int ub = __builtin_bit_cast(unsigned int, b) + 0x8000u;
  return __builtin_amdgcn_perm(ub, ua, 0x07060302u);
}
static __device__ __forceinline__ unsigned int pk2t(float a, float b) {
  return __builtin_amdgcn_perm(__builtin_bit_cast(unsigned int, b),
                               __builtin_bit_cast(unsigned int, a), 0x07060302u);
}
static __device__ __forceinline__ float fexp2(float x) {
  return __builtin_amdgcn_exp2f(x);
}
// 16B-aligned LDS ops: single ds_read_b128 / ds_write_b128
static __device__ __forceinline__ bf16x8 ld8a(const unsigned short* p) {
  return __builtin_bit_cast(bf16x8, *(const uint4*)p);
}
static __device__ __forceinline__ void st16a(unsigned short* p, uint4 v) {
  *(uint4*)p = v;
}
static __device__ __forceinline__ uint4 ld16u(const unsigned short* p) {
  uint2 a = *(const uint2*)p, b = *(const uint2*)(p + 4);
  return make_uint4(a.x, a.y, b.x, b.y);
}
static __device__ __forceinline__ void st16(unsigned short* p, uint4 v) {
  *(uint2*)p = make_uint2(v.x, v.y);
  *(uint2*)(p + 4) = make_uint2(v.z, v.w);
}
// sigma: phys key (0..31) -> MFMA m-row so QK C/D regs land in PV A order
static __device__ __forceinline__ int sig32(int q) {
  int s = q >> 4, h2 = (q >> 3) & 1, j = q & 7;
  return (s << 4) | ((j >> 2) << 3) | (h2 << 2) | (j & 3);
}

// ---------------------------------------------------------------------------
// Kernel 0: convert x (XN) + 4 weight matrices (WN each) fp32 -> bf16.
// grid 840 x 256, 8 elems/thread.
// ---------------------------------------------------------------------------
__global__ __launch_bounds__(256) void prep_kernel(
    const float* __restrict__ x, const float* __restrict__ Wq,
    const float* __restrict__ Wk, const float* __restrict__ Wv,
    const float* __restrict__ Wo, unsigned short* __restrict__ Xb,
    unsigned short* __restrict__ Wqb, unsigned short* __restrict__ Wkb,
    unsigned short* __restrict__ Wvb, unsigned short* __restrict__ Wob) {
  int idx = (blockIdx.x * 256 + threadIdx.x) * 8;
  const float* src;
  unsigned short* dst;
  int off;
  if (idx < XN) {
    src = x; dst = Xb; off = idx;
  } else {
    int r = idx - XN;
    int wsel = r / WN;
    off = r - wsel * WN;
    src = (wsel == 0) ? Wq : (wsel == 1) ? Wk : (wsel == 2) ? Wv : Wo;
    dst = (wsel == 0) ? Wqb : (wsel == 1) ? Wkb : (wsel == 2) ? Wvb : Wob;
  }
  float4 v0 = *(const float4*)(src + off), v1 = *(const float4*)(src + off + 4);
  *(uint4*)(dst + off) = make_uint4(pk2ru(v0.x, v0.y), pk2ru(v0.z, v0.w),
                                    pk2ru(v1.x, v1.y), pk2ru(v1.z, v1.w));
}

// ---------------------------------------------------------------------------
// Kernel 1: q/k/v = xb @ Wb^T (bf16 sources). 64x64 tile, BK=64, 5 K-iters,
// dbuf LDS (1 barrier/iter, prefetch dist 2). grid (64, 15): z = y/5,
// bnn = (y%5)*64. 4 waves in 2x2 layout. A/B stride 88 shorts (cf b128).
// ---------------------------------------------------------------------------
__global__ __launch_bounds__(256) void proj_qkv_kernel(
    const unsigned short* __restrict__ Xb, const unsigned short* __restrict__ Wqb,
    const unsigned short* __restrict__ Wkb, const unsigned short* __restrict__ Wvb,
    unsigned short* __restrict__ Qp, unsigned short* __restrict__ Kp,
    unsigned short* __restrict__ Vt) {
  const int zi = blockIdx.y;
  const int z = zi / 5;
  const int bnn = (zi - z * 5) * 64;
  const unsigned short* W = (z == 0) ? Wqb : (z == 1) ? Wkb : Wvb;
  __shared__ __align__(16) unsigned short As[2][64 * 88];
  __shared__ __align__(16) unsigned short Bs[2][64 * 88];
  const int t = threadIdx.x;
  const int w = t >> 6, l = t & 63, l31 = l & 31, hi = l >> 5;
  const int bm = blockIdx.x * 64;
  const int m0 = (w >> 1) * 32, n0 = (w & 1) * 32;
  f32x16 acc = {0,0,0,0,0,0,0,0,0,0,0,0,0,0,0,0};
  const int afo = (m0 + l31) * 88 + hi * 8;
  const int bfo = (n0 + l31) * 88 + hi * 8;
  const int row0 = t >> 3, row1 = row0 + 32, kc = (t & 7) << 3;
  const unsigned short* xb = Xb + (bm + row0) * ND + kc;
  const unsigned short* xb1 = Xb + (bm + row1) * ND + kc;
  const unsigned short* Wb = W + (bnn + row0) * ND + kc;
  const unsigned short* Wb1 = W + (bnn + row1) * ND + kc;
  const int so0 = row0 * 88 + kc, so1 = row1 * 88 + kc;

  uint4 a0v, a1v, b0v, b1v;
#define PQ_LOAD(K)                              \
  do {                                          \
    a0v = *(const uint4*)(xb + (K));            \
    a1v = *(const uint4*)(xb1 + (K));           \
    b0v = *(const uint4*)(Wb + (K));            \
    b1v = *(const uint4*)(Wb1 + (K));           \
  } while (0)
#define PQ_STORE(BUFI)                          \
  do {                                          \
    st16a(&As[BUFI][so0], a0v);                 \
    st16a(&As[BUFI][so1], a1v);                 \
    st16a(&Bs[BUFI][so0], b0v);                 \
    st16a(&Bs[BUFI][so1], b1v);                 \
  } while (0)

  PQ_LOAD(0);
  PQ_STORE(0);
  PQ_LOAD(64);
  __syncthreads();
#pragma unroll
  for (int it = 0; it < 5; ++it) {
    const int cur = it & 1, nxt = cur ^ 1;
    if (it < 4) PQ_STORE(nxt);                 // stage tile it+1
    {                                          // prefetch tile it+2 (clamped)
      int kp = (it + 2) * 64;
      if (kp >= ND) kp = 0;                    // wasted-but-safe reload
      PQ_LOAD(kp);
    }
#pragma unroll
    for (int kk = 0; kk < 4; kk++) {
      acc = __builtin_amdgcn_mfma_f32_32x32x16_bf16(
          ld8a(&As[cur][afo + kk * 16]), ld8a(&Bs[cur][bfo + kk * 16]), acc, 0, 0, 0);
    }
    __syncthreads();
  }
#undef PQ_LOAD
#undef PQ_STORE

  unsigned short* Tile = &As[0][0];            // compute done; reuse as Tile
  if (z < 2) {
    // ---- Q/K epilogue: Tile [64 rows][64 cols] stride 68 ----
    unsigned short* Y = (z == 0) ? Qp : Kp;
    const float sc = (z == 0) ? SCALE2 : 1.0f;
    const unsigned int padw = (z == 0) ? 0xC200u : 0x3F80u;  // -32.0 : 1.0
#pragma unroll
    for (int r2 = 0; r2 < 16; r2++) {
      int lr = m0 + (r2 & 3) + 8 * (r2 >> 2) + 4 * hi;
      Tile[lr * 68 + n0 + l31] = f2bru(acc[r2] * sc);
    }
    __syncthreads();
#pragma unroll
    for (int i = 0; i < 2; i++) {              // 64 rows x 8 chunks
      int c = t + i * 256;
      int row = c >> 3, ch = c & 7;
      int j = bnn + ch * 8;
      int h = j / 40, dh = j - h * 40;
      uint4 v = ld16u(Tile + row * 68 + ch * 8);
      st16(Y + h * HS48 + (bm + row) * 48 + dh, v);
      if (dh == 0)
        st16(Y + h * HS48 + (bm + row) * 48 + 40, make_uint4(padw, 0u, 0u, 0u));
    }
  } else {
    // ---- V epilogue: transposed Tile [64 j][64 s] stride 68 ----
#pragma unroll
    for (int r2 = 0; r2 < 16; r2++) {
      int lr = m0 + (r2 & 3) + 8 * (r2 >> 2) + 4 * hi;
      Tile[(n0 + l31) * 68 + lr] = f2bru(acc[r2]);
    }
    __syncthreads();
#pragma unroll
    for (int i = 0; i < 2; i++) {              // 64 j-rows x 8 s-chunks
      int c = t + i * 256;
      int row = c >> 3, ch = c & 7;
      int j = bnn + row;
      int h = j / 40, dd = j - h * 40;
      uint4 v = ld16u(Tile + row * 68 + ch * 8);
      st16(Vt + h * VTH + dd * NS + bm + ch * 8, v);
    }
  }
}

// ---------------------------------------------------------------------------
// Kernel 2: MFMA flash attention (R6 body, plain epilogue). grid 512 x 256.
// h=b&7 XCD swizzle, ks=2 key-splits of 2048 keys, 32 iters of 64-key tiles.
// Double-buffered LDS, 1 barrier/iter, prefetch-2, 16B-aligned odd-stride.
// ---------------------------------------------------------------------------
__global__ __launch_bounds__(256, 4) void attn_kernel(
    const unsigned short* __restrict__ Qp, const unsigned short* __restrict__ Kp,
    const unsigned short* __restrict__ Vt, unsigned short* __restrict__ Op,
    float* __restrict__ Lp) {
  const int b = blockIdx.x;
  const int h = b & 7, ks = (b >> 3) & 1, qt = b >> 4;   // qt in 0..31
  const int t = threadIdx.x;
  const int w = t >> 6, l = t & 63, l31 = l & 31, hi = l >> 5;
  __shared__ __align__(16) unsigned short Lds[2 * BUF];
  // V rows 40..47 in BOTH buffers: row 40 = ones (cols 0..63), rest zero.
  for (int i = t; i < 576; i += 256) {
    int bsel = (i >= 288) ? 1 : 0;
    int ui = i - bsel * 288;
    int rr = ui / 36, cc = ui - rr * 36;
    ((unsigned int*)Lds)[bsel * (BUF / 2) + (VB / 2) + (40 + rr) * 36 + cc] =
        (rr == 0 && cc < 32) ? 0x3F803F80u : 0u;
  }

  const int kbase = ks * 2048;
  const int qbase = qt * 128 + w * 32;
  const unsigned short* qp = Qp + h * HS48 + (qbase + l31) * 48 + hi * 8;
  bf16x8 qf0 = *(const bf16x8*)qp;
  bf16x8 qf1 = *(const bf16x8*)(qp + 16);
  bf16x8 qf2 = *(const bf16x8*)(qp + 32);   // includes {-32,0..} pad

  const f32x16 Z = {0,0,0,0,0,0,0,0,0,0,0,0,0,0,0,0};  // hoisted zero-C
  f32x16 oa0 = Z, oa1 = Z;

  // unified staging map: chunk ids 0..383 = K (kr=id/6, kc=id%6),
  // ids 384..703 = V (vr=(id-384)>>3 in 0..39, vc=(id-384)&7).
  const int id1 = t + 256;
  const bool has2 = (t < 192);
  const int kr0 = t / 6, kc0 = t - kr0 * 6;
  const unsigned short* g0 = Kp + h * HS48 + (kbase + kr0) * 48 + kc0 * 8;
  const int w0 = ((kr0 & 32) | sig32(kr0 & 31)) * KSTR + kc0 * 8;
  const unsigned short* g1;
  int w1, inc1;
  if (id1 < 384) {
    int kr = id1 / 6, kc = id1 - kr * 6;
    g1 = Kp + h * HS48 + (kbase + kr) * 48 + kc * 8;
    w1 = ((kr & 32) | sig32(kr & 31)) * KSTR + kc * 8;
    inc1 = 64 * 48;
  } else {
    int vid = id1 - 384, vr = vid >> 3, vc = vid & 7;
    g1 = Vt + h * VTH + vr * NS + kbase + vc * 8;
    w1 = VB + vr * VSTR + vc * 8;
    inc1 = 64;
  }
  const int vid2 = t + 128;                   // id2 - 384, valid for t<192
  const int vr2 = vid2 >> 3, vc2 = vid2 & 7;  // rows 16..39
  const unsigned short* g2 = Vt + h * VTH + vr2 * NS + kbase + vc2 * 8;
  const int w2 = VB + vr2 * VSTR + vc2 * 8;

  const int rk  = l31 * KSTR + hi * 8;                 // kf0 (+32*KSTR = kf1)
  const int rv0 = VB + l31 * VSTR + hi * 8;
  const int rv1 = VB + (32 + (l31 & 15)) * VSTR + hi * 8;

  // prologue: tile 0 -> buf0, tile 1 -> regs
  uint4 r0 = *(const uint4*)g0; g0 += 3072;
  uint4 r1 = *(const uint4*)g1; g1 += inc1;
  uint4 r2{};
  if (has2) { r2 = *(const uint4*)g2; g2 += 64; }
  st16a(Lds + w0, r0);
  st16a(Lds + w1, r1);
  if (has2) st16a(Lds + w2, r2);
  r0 = *(const uint4*)g0; g0 += 3072;
  r1 = *(const uint4*)g1; g1 += inc1;
  if (has2) { r2 = *(const uint4*)g2; g2 += 64; }
  __syncthreads();

  for (int it = 0; it < 32; ++it) {
    const int bo = (it & 1) ? BUF : 0;
    const int bn = BUF - bo;
    // stage tile it+1 into the other buffer; issue loads for tile it+2.
    st16a(Lds + bn + w0, r0);
    st16a(Lds + bn + w1, r1);
    if (has2) st16a(Lds + bn + w2, r2);
    r0 = *(const uint4*)g0; g0 += 3072;
    r1 = *(const uint4*)g1; g1 += inc1;
    if (has2) { r2 = *(const uint4*)g2; g2 += 64; }

    const unsigned short* kf0 = Lds + bo + rk;
    const unsigned short* kf1 = kf0 + 32 * KSTR;
    const unsigned short* vf0 = Lds + bo + rv0;
    const unsigned short* vf1 = Lds + bo + rv1;

    __builtin_amdgcn_s_setprio(1);
    {  // m-tile 0: phys keys 0..31 (sigma rows)
      f32x16 s0 = __builtin_amdgcn_mfma_f32_32x32x16_bf16(ld8a(kf0), qf0, Z, 0, 0, 0);
      s0 = __builtin_amdgcn_mfma_f32_32x32x16_bf16(ld8a(kf0 + 16), qf1, s0, 0, 0, 0);
      s0 = __builtin_amdgcn_mfma_f32_32x32x16_bf16(ld8a(kf0 + 32), qf2, s0, 0, 0, 0);
      unsigned int pw[8];
#pragma unroll
      for (int i = 0; i < 8; i++)
        pw[i] = pk2t(fexp2(s0[2 * i]), fexp2(s0[2 * i + 1]));
      bf16x8 pf0 = __builtin_bit_cast(bf16x8, make_uint4(pw[0], pw[1], pw[2], pw[3]));
      bf16x8 pf1 = __builtin_bit_cast(bf16x8, make_uint4(pw[4], pw[5], pw[6], pw[7]));
      oa0 = __builtin_amdgcn_mfma_f32_32x32x16_bf16(pf0, ld8a(vf0), oa0, 0, 0, 0);
      oa1 = __builtin_amdgcn_mfma_f32_32x32x16_bf16(pf0, ld8a(vf1), oa1, 0, 0, 0);
      oa0 = __builtin_amdgcn_mfma_f32_32x32x16_bf16(pf1, ld8a(vf0 + 16), oa0, 0, 0, 0);
      oa1 = __builtin_amdgcn_mfma_f32_32x32x16_bf16(pf1, ld8a(vf1 + 16), oa1, 0, 0, 0);
    }
    {  // m-tile 1: phys keys 32..63
      f32x16 s1 = __builtin_amdgcn_mfma_f32_32x32x16_bf16(ld8a(kf1), qf0, Z, 0, 0, 0);
      s1 = __builtin_amdgcn_mfma_f32_32x32x16_bf16(ld8a(kf1 + 16), qf1, s1, 0, 0, 0);
      s1 = __builtin_amdgcn_mfma_f32_32x32x16_bf16(ld8a(kf1 + 32), qf2, s1, 0, 0, 0);
      unsigned int pw[8];
#pragma unroll
      for (int i = 0; i < 8; i++)
        pw[i] = pk2t(fexp2(s1[2 * i]), fexp2(s1[2 * i + 1]));
      bf16x8 pf2 = __builtin_bit_cast(bf16x8, make_uint4(pw[0], pw[1], pw[2], pw[3]));
      bf16x8 pf3 = __builtin_bit_cast(bf16x8, make_uint4(pw[4], pw[5], pw[6], pw[7]));
      oa0 = __builtin_amdgcn_mfma_f32_32x32x16_bf16(pf2, ld8a(vf0 + 32), oa0, 0, 0, 0);
      oa1 = __builtin_amdgcn_mfma_f32_32x32x16_bf16(pf2, ld8a(vf1 + 32), oa1, 0, 0, 0);
      oa0 = __builtin_amdgcn_mfma_f32_32x32x16_bf16(pf3, ld8a(vf0 + 48), oa0, 0, 0, 0);
      oa1 = __builtin_amdgcn_mfma_f32_32x32x16_bf16(pf3, ld8a(vf1 + 48), oa1, 0, 0, 0);
    }
    __builtin_amdgcn_s_setprio(0);
    __syncthreads();
  }

  unsigned short* opb = Op + ks * XN + h * 163840;
  float* lpb = Lp + ks * 32768 + h * NS;
#pragma unroll
  for (int r2i = 0; r2i < 16; r2i++) {
    int qr = qbase + (r2i & 3) + 8 * (r2i >> 2) + 4 * hi;
    opb[qr * 40 + l31] = f2bru(oa0[r2i]);
    if (l31 < 8) opb[qr * 40 + 32 + l31] = f2bru(oa1[r2i]);
    if (l31 == 8) lpb[qr] = oa1[r2i];   // l = Sum(p) via ones-row at dh=40
  }
}

// ---------------------------------------------------------------------------
// Kernel 3: sum 2 bf16 partials, normalize -> Xo [s][320] bf16.
// grid 640 x 256, 8 elems/thread (uint4); 40 % 8 == 0 so a uint4 never
// crosses a head/row boundary.
// ---------------------------------------------------------------------------
__global__ __launch_bounds__(256) void combine_kernel(
    const unsigned short* __restrict__ Op, const float* __restrict__ Lp,
    unsigned short* __restrict__ Xo) {
  int e = (blockIdx.x * 256 + threadIdx.x) * 8;    // over [h][s][40]
  int h = e / 163840;
  int r = e - h * 163840;
  int s = r / 40;
  int dh = r - s * 40;
  float a[8] = {0, 0, 0, 0, 0, 0, 0, 0};
  float lsum = 0.f;
#pragma unroll
  for (int k = 0; k < 2; k++) {
    uint4 u = *(const uint4*)(Op + k * XN + e);
    a[0] += __builtin_bit_cast(float, u.x << 16);
    a[1] += __builtin_bit_cast(float, u.x & 0xFFFF0000u);
    a[2] += __builtin_bit_cast(float, u.y << 16);
    a[3] += __builtin_bit_cast(float, u.y & 0xFFFF0000u);
    a[4] += __builtin_bit_cast(float, u.z << 16);
    a[5] += __builtin_bit_cast(float, u.z & 0xFFFF0000u);
    a[6] += __builtin_bit_cast(float, u.w << 16);
    a[7] += __builtin_bit_cast(float, u.w & 0xFFFF0000u);
    lsum += Lp[k * 32768 + h * NS + s];
  }
  float inv = 1.0f / lsum;
  *(uint4*)(Xo + s * ND + h * 40 + dh) =
      make_uint4(pk2ru(a[0] * inv, a[1] * inv), pk2ru(a[2] * inv, a[3] * inv),
                 pk2ru(a[4] * inv, a[5] * inv), pk2ru(a[6] * inv, a[7] * inv));
}

// ---------------------------------------------------------------------------
// Kernel 4: out = Xo @ Wob^T + bo (bf16 sources). 64x64 tile, BK=64, 5
// iters, grid (64, 5) = 320 blocks. 4 waves in 2x2 layout. A/B stride 88.
// ---------------------------------------------------------------------------
__global__ __launch_bounds__(256) void proj_out_kernel(
    const unsigned short* __restrict__ Xo, const unsigned short* __restrict__ Wob,
    const float* __restrict__ bo, float* __restrict__ out) {
  __shared__ __align__(16) unsigned short As[64 * 88];
  __shared__ __align__(16) unsigned short Bs[64 * 88];
  const int t = threadIdx.x;
  const int w = t >> 6, l = t & 63, l31 = l & 31, hi = l >> 5;
  const int bm = blockIdx.x * 64;
  const int bnn = blockIdx.y * 64;
  const int m0 = (w >> 1) * 32, n0 = (w & 1) * 32;
  f32x16 acc = {0,0,0,0,0,0,0,0,0,0,0,0,0,0,0,0};
  const unsigned short* af = As + (m0 + l31) * 88 + hi * 8;
  const unsigned short* bf = Bs + (n0 + l31) * 88 + hi * 8;
  for (int k0 = 0; k0 < ND; k0 += 64) {
    __syncthreads();
#pragma unroll
    for (int i = 0; i < 2; i++) {            // A: 64 rows x 8 chunks, bf16 src
      int c = t + i * 256;
      int row = c >> 3, kc = (c & 7) << 3;
      uint4 v = *(const uint4*)(Xo + (bm + row) * ND + k0 + kc);
      st16a(As + row * 88 + kc, v);
    }
#pragma unroll
    for (int i = 0; i < 2; i++) {            // B: 64 rows x 8 chunks, bf16 src
      int c = t + i * 256;
      int row = c >> 3, kc = (c & 7) << 3;
      uint4 v = *(const uint4*)(Wob + (bnn + row) * ND + k0 + kc);
      st16a(Bs + row * 88 + kc, v);
    }
    __syncthreads();
#pragma unroll
    for (int ks = 0; ks < 4; ks++) {
      acc = __builtin_amdgcn_mfma_f32_32x32x16_bf16(
          ld8a(af + ks * 16), ld8a(bf + ks * 16), acc, 0, 0, 0);
    }
  }
  const int j = bnn + n0 + l31;
  const float bj = bo[j];
#pragma unroll
  for (int r2 = 0; r2 < 16; r2++) {
    int row = bm + m0 + (r2 & 3) + 8 * (r2 >> 2) + 4 * hi;
    out[row * ND + j] = acc[r2] + bj;
  }
}

extern "C" void kernel_launch(void* const* d_in, const int* in_sizes, int n_in,
                              void* d_out, int out_size, void* d_ws, size_t ws_size,
                              hipStream_t stream) {
  (void)in_sizes; (void)n_in; (void)out_size; (void)ws_size;
  const float* x  = (const float*)d_in[0];
  const float* Wq = (const float*)d_in[1];
  const float* Wk = (const float*)d_in[2];
  const float* Wv = (const float*)d_in[3];
  const float* Wo = (const float*)d_in[4];
  const float* bo = (const float*)d_in[5];
  float* out = (float*)d_out;

  unsigned short* Qp = (unsigned short*)d_ws;   // 8*HS48
  unsigned short* Kp = Qp + 8 * HS48;           // 8*HS48
  unsigned short* Vt = Kp + 8 * HS48;           // 8*VTH
  unsigned short* Xo = Vt + 8 * VTH;            // XN
  unsigned short* Op = Xo + XN;                 // 2*XN bf16 partials
  float* Lp = (float*)(Op + 2 * XN);            // 2*32768 fp32
  unsigned short* Xb = (unsigned short*)(Lp + 65536);   // XN bf16 x
  unsigned short* Wqb = Xb + XN;                // WN each, bf16 weights
  unsigned short* Wkb = Wqb + WN;
  unsigned short* Wvb = Wkb + WN;
  unsigned short* Wob = Wvb + WN;
  // ws use ~21 MB

  prep_kernel<<<dim3(840), 256, 0, stream>>>(x, Wq, Wk, Wv, Wo,
                                             Xb, Wqb, Wkb, Wvb, Wob);
  proj_qkv_kernel<<<dim3(64, 15), 256, 0, stream>>>(Xb, Wqb, Wkb, Wvb,
                                                    Qp, Kp, Vt);
  attn_kernel<<<dim3(512), 256, 0, stream>>>(Qp, Kp, Vt, Op, Lp);
  combine_kernel<<<dim3(640), 256, 0, stream>>>(Op, Lp, Xo);
  proj_out_kernel<<<dim3(64, 5), 256, 0, stream>>>(Xo, Wob, bo, out);
}

// Round 10
// 118.240 us; speedup vs baseline: 1.3590x; 1.0215x over previous
//
#include <hip/hip_runtime.h>
#include <math.h>

// B=1, S=4096, H=8, DH=40, D=320, fp32 in/out.  THREE kernels (R10):
// proj_qkv: 64x64-tile MFMA GEMM, BK=64, dbuf LDS (1 barrier/iter, prefetch
//           dist 2), fp32 srcs -> Qp/Kp [h][s][48] (Q pre-scaled; pad -32),
//           Vt [h][40][4096].
// attn:     MFMA flash, INTRA-BLOCK split-K: 512 thr (8 waves), grid 256
//           (8h x 32qt, 1 block/CU, 2 waves/SIMD = same TLP as R6).
//           Wave group g = keys g*2048..+2047, own dbuf pipeline (56KB LDS).
//           Block-local merge via LDS (no fences! R8 lesson), normalize
//           in-register, write Xo directly. Kills combine kernel + Op/Lp
//           traffic + 2 launch gaps (prep also dropped, ~neutral in R9).
// proj_out: 64x64-tile MFMA GEMM + bias, grid (64,5) -> out fp32.
// R8 lesson: device fences during concurrent compute = L2 invalidate storm.
// R7 lesson: hipLaunchCooperativeKernel silently no-ops under graph capture.
// NOTE: harness re-poison (~41us fillBuffer of 268MB ws) is inside the timed
// window and fixed.

#define NS 4096
#define ND 320
#define SCALE2 0.2281101152f      // log2(e)/sqrt(40)
#define HS48 196608               // 4096*48 per head
#define VTH 163840                // 40*4096 per head
#define XN 1310720

// attn LDS geometry (shorts)
#define KSTR 56                   // K row stride: 112B = 7 chunks (odd -> cf)
#define VSTR 72                   // V row stride: 144B = 9 chunks (odd -> cf)
#define VB   3584                 // 64*KSTR
#define BUF  7040                 // VB + 48*VSTR (one buffer)

typedef __attribute__((ext_vector_type(8))) short bf16x8;
typedef __attribute__((ext_vector_type(16))) float f32x16;

static __device__ __forceinline__ unsigned short f2bru(float f) {
  return (unsigned short)((__builtin_bit_cast(unsigned int, f) + 0x8000u) >> 16);
}
static __device__ __forceinline__ unsigned int pk2ru(float a, float b) {
  unsigned int ua = __builtin_bit_cast(unsigned int, a) + 0x8000u;
  unsigned int ub = __builtin_bit_cast(unsigned int, b) + 0x8000u;
  return __builtin_amdgcn_perm(ub, ua, 0x07060302u);
}
static __device__ __forceinline__ unsigned int pk2t(float a, float b) {
  return __builtin_amdgcn_perm(__builtin_bit_cast(unsigned int, b),
                               __builtin_bit_cast(unsigned int, a), 0x07060302u);
}
static __device__ __forceinline__ float fexp2(float x) {
  return __builtin_amdgcn_exp2f(x);
}
// 16B-aligned LDS ops: single ds_read_b128 / ds_write_b128
static __device__ __forceinline__ bf16x8 ld8a(const unsigned short* p) {
  return __builtin_bit_cast(bf16x8, *(const uint4*)p);
}
static __device__ __forceinline__ void st16a(unsigned short* p, uint4 v) {
  *(uint4*)p = v;
}
static __device__ __forceinline__ uint4 ld16u(const unsigned short* p) {
  uint2 a = *(const uint2*)p, b = *(const uint2*)(p + 4);
  return make_uint4(a.x, a.y, b.x, b.y);
}
static __device__ __forceinline__ void st16(unsigned short* p, uint4 v) {
  *(uint2*)p = make_uint2(v.x, v.y);
  *(uint2*)(p + 4) = make_uint2(v.z, v.w);
}
// sigma: phys key (0..31) -> MFMA m-row so QK C/D regs land in PV A order
static __device__ __forceinline__ int sig32(int q) {
  int s = q >> 4, h2 = (q >> 3) & 1, j = q & 7;
  return (s << 4) | ((j >> 2) << 3) | (h2 << 2) | (j & 3);
}

// ---------------------------------------------------------------------------
// Kernel 1: q/k/v = x @ W^T. 64x64 tile, BK=64, 5 K-iters, dbuf LDS
// (1 barrier/iter, prefetch dist 2). grid (64, 15): z = y/5, bnn = (y%5)*64.
// 4 waves in 2x2 layout. A/B stride 88 shorts (odd-chunk, cf b128).
// ---------------------------------------------------------------------------
__global__ __launch_bounds__(256) void proj_qkv_kernel(
    const float* __restrict__ x, const float* __restrict__ Wq,
    const float* __restrict__ Wk, const float* __restrict__ Wv,
    unsigned short* __restrict__ Qp, unsigned short* __restrict__ Kp,
    unsigned short* __restrict__ Vt) {
  const int zi = blockIdx.y;
  const int z = zi / 5;
  const int bnn = (zi - z * 5) * 64;
  const float* W = (z == 0) ? Wq : (z == 1) ? Wk : Wv;
  __shared__ __align__(16) unsigned short As[2][64 * 88];
  __shared__ __align__(16) unsigned short Bs[2][64 * 88];
  const int t = threadIdx.x;
  const int w = t >> 6, l = t & 63, l31 = l & 31, hi = l >> 5;
  const int bm = blockIdx.x * 64;
  const int m0 = (w >> 1) * 32, n0 = (w & 1) * 32;
  f32x16 acc = {0,0,0,0,0,0,0,0,0,0,0,0,0,0,0,0};
  const int afo = (m0 + l31) * 88 + hi * 8;
  const int bfo = (n0 + l31) * 88 + hi * 8;
  const int row0 = t >> 3, row1 = row0 + 32, kc = (t & 7) << 3;
  const float* xb = x + (bm + row0) * ND + kc;
  const float* xb1 = x + (bm + row1) * ND + kc;
  const float* Wb = W + (bnn + row0) * ND + kc;
  const float* Wb1 = W + (bnn + row1) * ND + kc;
  const int so0 = row0 * 88 + kc, so1 = row1 * 88 + kc;

  float4 a00, a01, a10, a11, b00, b01, b10, b11;
#define PQ_LOAD(K)                                                   \
  do {                                                               \
    a00 = *(const float4*)(xb + (K));  a01 = *(const float4*)(xb + (K) + 4);  \
    a10 = *(const float4*)(xb1 + (K)); a11 = *(const float4*)(xb1 + (K) + 4); \
    b00 = *(const float4*)(Wb + (K));  b01 = *(const float4*)(Wb + (K) + 4);  \
    b10 = *(const float4*)(Wb1 + (K)); b11 = *(const float4*)(Wb1 + (K) + 4); \
  } while (0)
#define PQ_STORE(BUFI)                                               \
  do {                                                               \
    st16a(&As[BUFI][so0], make_uint4(pk2ru(a00.x, a00.y), pk2ru(a00.z, a00.w), \
                                     pk2ru(a01.x, a01.y), pk2ru(a01.z, a01.w))); \
    st16a(&As[BUFI][so1], make_uint4(pk2ru(a10.x, a10.y), pk2ru(a10.z, a10.w), \
                                     pk2ru(a11.x, a11.y), pk2ru(a11.z, a11.w))); \
    st16a(&Bs[BUFI][so0], make_uint4(pk2ru(b00.x, b00.y), pk2ru(b00.z, b00.w), \
                                     pk2ru(b01.x, b01.y), pk2ru(b01.z, b01.w))); \
    st16a(&Bs[BUFI][so1], make_uint4(pk2ru(b10.x, b10.y), pk2ru(b10.z, b10.w), \
                                     pk2ru(b11.x, b11.y), pk2ru(b11.z, b11.w))); \
  } while (0)

  PQ_LOAD(0);
  PQ_STORE(0);
  PQ_LOAD(64);
  __syncthreads();
#pragma unroll
  for (int it = 0; it < 5; ++it) {
    const int cur = it & 1, nxt = cur ^ 1;
    if (it < 4) PQ_STORE(nxt);                 // stage tile it+1
    {                                          // prefetch tile it+2 (clamped)
      int kp = (it + 2) * 64;
      if (kp >= ND) kp = 0;                    // wasted-but-safe reload
      PQ_LOAD(kp);
    }
#pragma unroll
    for (int kk = 0; kk < 4; kk++) {
      acc = __builtin_amdgcn_mfma_f32_32x32x16_bf16(
          ld8a(&As[cur][afo + kk * 16]), ld8a(&Bs[cur][bfo + kk * 16]), acc, 0, 0, 0);
    }
    __syncthreads();
  }
#undef PQ_LOAD
#undef PQ_STORE

  unsigned short* Tile = &As[0][0];            // compute done; reuse as Tile
  if (z < 2) {
    // ---- Q/K epilogue: Tile [64 rows][64 cols] stride 68 ----
    unsigned short* Y = (z == 0) ? Qp : Kp;
    const float sc = (z == 0) ? SCALE2 : 1.0f;
    const unsigned int padw = (z == 0) ? 0xC200u : 0x3F80u;  // -32.0 : 1.0
#pragma unroll
    for (int r2 = 0; r2 < 16; r2++) {
      int lr = m0 + (r2 & 3) + 8 * (r2 >> 2) + 4 * hi;
      Tile[lr * 68 + n0 + l31] = f2bru(acc[r2] * sc);
    }
    __syncthreads();
#pragma unroll
    for (int i = 0; i < 2; i++) {              // 64 rows x 8 chunks
      int c = t + i * 256;
      int row = c >> 3, ch = c & 7;
      int j = bnn + ch * 8;
      int h = j / 40, dh = j - h * 40;
      uint4 v = ld16u(Tile + row * 68 + ch * 8);
      st16(Y + h * HS48 + (bm + row) * 48 + dh, v);
      if (dh == 0)
        st16(Y + h * HS48 + (bm + row) * 48 + 40, make_uint4(padw, 0u, 0u, 0u));
    }
  } else {
    // ---- V epilogue: transposed Tile [64 j][64 s] stride 68 ----
#pragma unroll
    for (int r2 = 0; r2 < 16; r2++) {
      int lr = m0 + (r2 & 3) + 8 * (r2 >> 2) + 4 * hi;
      Tile[(n0 + l31) * 68 + lr] = f2bru(acc[r2]);
    }
    __syncthreads();
#pragma unroll
    for (int i = 0; i < 2; i++) {              // 64 j-rows x 8 s-chunks
      int c = t + i * 256;
      int row = c >> 3, ch = c & 7;
      int j = bnn + row;
      int h = j / 40, dd = j - h * 40;
      uint4 v = ld16u(Tile + row * 68 + ch * 8);
      st16(Vt + h * VTH + dd * NS + bm + ch * 8, v);
    }
  }
}

// ---------------------------------------------------------------------------
// Kernel 2: MFMA flash attention, intra-block split-K. 512 thr (8 waves),
// grid 256 (h = b&7 XCD swizzle, qt = b>>3). Wave group g = t>>8 handles
// keys [g*2048, +2048) for the same 128 q-rows (wave-in-group w owns 32).
// Per group: private dbuf LDS pipeline (2xBUF shorts), 1 barrier/iter
// (barrier spans both groups -- symmetric work, lockstep), prefetch dist 2.
// End: group 1 dumps acc to LDS, group 0 adds, normalizes via shfl'd
// ones-row sum, writes Xo directly. Block-local merge -- NO fences.
// Exponent offset (-32 via Q pad) is uniform -> partials add exactly.
// ---------------------------------------------------------------------------
__global__ __launch_bounds__(512, 2) void attn_kernel(
    const unsigned short* __restrict__ Qp, const unsigned short* __restrict__ Kp,
    const unsigned short* __restrict__ Vt, unsigned short* __restrict__ Xo) {
  const int b = blockIdx.x;
  const int h = b & 7, qt = b >> 3;   // qt in 0..31
  const int t = threadIdx.x;          // 0..511
  const int g = t >> 8;               // key-split group 0/1
  const int lt = t & 255;             // tid within group
  const int w = lt >> 6;              // wave-in-group 0..3
  const int l = t & 63, l31 = l & 31, hi = l >> 5;
  __shared__ __align__(16) unsigned short Lds[4 * BUF];   // 56320 B
  unsigned short* gl = Lds + g * (2 * BUF);               // group's 2 buffers
  // V rows 40..47 in this group's BOTH buffers: row 40 = ones, rest zero.
  for (int i = lt; i < 576; i += 256) {
    int bsel = (i >= 288) ? 1 : 0;
    int ui = i - bsel * 288;
    int rr = ui / 36, cc = ui - rr * 36;
    ((unsigned int*)gl)[bsel * (BUF / 2) + (VB / 2) + (40 + rr) * 36 + cc] =
        (rr == 0 && cc < 32) ? 0x3F803F80u : 0u;
  }

  const int kbase = g * 2048;
  const int qbase = qt * 128 + w * 32;
  const unsigned short* qp = Qp + h * HS48 + (qbase + l31) * 48 + hi * 8;
  bf16x8 qf0 = *(const bf16x8*)qp;
  bf16x8 qf1 = *(const bf16x8*)(qp + 16);
  bf16x8 qf2 = *(const bf16x8*)(qp + 32);   // includes {-32,0..} pad

  const f32x16 Z = {0,0,0,0,0,0,0,0,0,0,0,0,0,0,0,0};  // hoisted zero-C
  f32x16 oa0 = Z, oa1 = Z;

  // unified staging map (per group): chunk ids 0..383 = K (kr=id/6, kc=id%6),
  // ids 384..703 = V (vr=(id-384)>>3 in 0..39, vc=(id-384)&7).
  // group-thread lt owns ids {lt, lt+256, lt+512(if lt<192)}.
  const int id1 = lt + 256;
  const bool has2 = (lt < 192);
  const int kr0 = lt / 6, kc0 = lt - kr0 * 6;
  const unsigned short* g0 = Kp + h * HS48 + (kbase + kr0) * 48 + kc0 * 8;
  const int w0 = ((kr0 & 32) | sig32(kr0 & 31)) * KSTR + kc0 * 8;
  const unsigned short* g1;
  int w1, inc1;
  if (id1 < 384) {
    int kr = id1 / 6, kc = id1 - kr * 6;
    g1 = Kp + h * HS48 + (kbase + kr) * 48 + kc * 8;
    w1 = ((kr & 32) | sig32(kr & 31)) * KSTR + kc * 8;
    inc1 = 64 * 48;
  } else {
    int vid = id1 - 384, vr = vid >> 3, vc = vid & 7;
    g1 = Vt + h * VTH + vr * NS + kbase + vc * 8;
    w1 = VB + vr * VSTR + vc * 8;
    inc1 = 64;
  }
  const int vid2 = lt + 128;                  // id2 - 384, valid for lt<192
  const int vr2 = vid2 >> 3, vc2 = vid2 & 7;  // rows 16..39
  const unsigned short* g2 = Vt + h * VTH + vr2 * NS + kbase + vc2 * 8;
  const int w2 = VB + vr2 * VSTR + vc2 * 8;

  const int rk  = l31 * KSTR + hi * 8;                 // kf0 (+32*KSTR = kf1)
  const int rv0 = VB + l31 * VSTR + hi * 8;
  const int rv1 = VB + (32 + (l31 & 15)) * VSTR + hi * 8;

  // prologue: tile 0 -> buf0, tile 1 -> regs
  uint4 r0 = *(const uint4*)g0; g0 += 3072;
  uint4 r1 = *(const uint4*)g1; g1 += inc1;
  uint4 r2{};
  if (has2) { r2 = *(const uint4*)g2; g2 += 64; }
  st16a(gl + w0, r0);
  st16a(gl + w1, r1);
  if (has2) st16a(gl + w2, r2);
  r0 = *(const uint4*)g0; g0 += 3072;
  r1 = *(const uint4*)g1; g1 += inc1;
  if (has2) { r2 = *(const uint4*)g2; g2 += 64; }
  __syncthreads();

  for (int it = 0; it < 32; ++it) {
    const int bo = (it & 1) ? BUF : 0;
    const int bn = BUF - bo;
    // stage tile it+1 into the other buffer; issue loads for tile it+2.
    // (last-iter overrun reads land in adjacent ws regions -- harmless)
    st16a(gl + bn + w0, r0);
    st16a(gl + bn + w1, r1);
    if (has2) st16a(gl + bn + w2, r2);
    r0 = *(const uint4*)g0; g0 += 3072;
    r1 = *(const uint4*)g1; g1 += inc1;
    if (has2) { r2 = *(const uint4*)g2; g2 += 64; }

    const unsigned short* kf0 = gl + bo + rk;
    const unsigned short* kf1 = kf0 + 32 * KSTR;
    const unsigned short* vf0 = gl + bo + rv0;
    const unsigned short* vf1 = gl + bo + rv1;

    __builtin_amdgcn_s_setprio(1);
    {  // m-tile 0: phys keys 0..31 (sigma rows)
      f32x16 s0 = __builtin_amdgcn_mfma_f32_32x32x16_bf16(ld8a(kf0), qf0, Z, 0, 0, 0);
      s0 = __builtin_amdgcn_mfma_f32_32x32x16_bf16(ld8a(kf0 + 16), qf1, s0, 0, 0, 0);
      s0 = __builtin_amdgcn_mfma_f32_32x32x16_bf16(ld8a(kf0 + 32), qf2, s0, 0, 0, 0);
      unsigned int pw[8];
#pragma unroll
      for (int i = 0; i < 8; i++)
        pw[i] = pk2t(fexp2(s0[2 * i]), fexp2(s0[2 * i + 1]));
      bf16x8 pf0 = __builtin_bit_cast(bf16x8, make_uint4(pw[0], pw[1], pw[2], pw[3]));
      bf16x8 pf1 = __builtin_bit_cast(bf16x8, make_uint4(pw[4], pw[5], pw[6], pw[7]));
      oa0 = __builtin_amdgcn_mfma_f32_32x32x16_bf16(pf0, ld8a(vf0), oa0, 0, 0, 0);
      oa1 = __builtin_amdgcn_mfma_f32_32x32x16_bf16(pf0, ld8a(vf1), oa1, 0, 0, 0);
      oa0 = __builtin_amdgcn_mfma_f32_32x32x16_bf16(pf1, ld8a(vf0 + 16), oa0, 0, 0, 0);
      oa1 = __builtin_amdgcn_mfma_f32_32x32x16_bf16(pf1, ld8a(vf1 + 16), oa1, 0, 0, 0);
    }
    {  // m-tile 1: phys keys 32..63
      f32x16 s1 = __builtin_amdgcn_mfma_f32_32x32x16_bf16(ld8a(kf1), qf0, Z, 0, 0, 0);
      s1 = __builtin_amdgcn_mfma_f32_32x32x16_bf16(ld8a(kf1 + 16), qf1, s1, 0, 0, 0);
      s1 = __builtin_amdgcn_mfma_f32_32x32x16_bf16(ld8a(kf1 + 32), qf2, s1, 0, 0, 0);
      unsigned int pw[8];
#pragma unroll
      for (int i = 0; i < 8; i++)
        pw[i] = pk2t(fexp2(s1[2 * i]), fexp2(s1[2 * i + 1]));
      bf16x8 pf2 = __builtin_bit_cast(bf16x8, make_uint4(pw[0], pw[1], pw[2], pw[3]));
      bf16x8 pf3 = __builtin_bit_cast(bf16x8, make_uint4(pw[4], pw[5], pw[6], pw[7]));
      oa0 = __builtin_amdgcn_mfma_f32_32x32x16_bf16(pf2, ld8a(vf0 + 32), oa0, 0, 0, 0);
      oa1 = __builtin_amdgcn_mfma_f32_32x32x16_bf16(pf2, ld8a(vf1 + 32), oa1, 0, 0, 0);
      oa0 = __builtin_amdgcn_mfma_f32_32x32x16_bf16(pf3, ld8a(vf0 + 48), oa0, 0, 0, 0);
      oa1 = __builtin_amdgcn_mfma_f32_32x32x16_bf16(pf3, ld8a(vf1 + 48), oa1, 0, 0, 0);
    }
    __builtin_amdgcn_s_setprio(0);
    __syncthreads();
  }

  // ---- block-local split-K merge (after final barrier: all compute done) --
  float* fl = (float*)Lds;                 // 8192 floats = 32KB (fits 56KB)
  const int slot = (w * 64 + l) * 32;
  if (g == 1) {
#pragma unroll
    for (int i = 0; i < 16; i++) {
      fl[slot + i] = oa0[i];
      fl[slot + 16 + i] = oa1[i];
    }
  }
  __syncthreads();
  if (g == 0) {
#pragma unroll
    for (int i = 0; i < 16; i++) {
      oa0[i] += fl[slot + i];
      oa1[i] += fl[slot + 16 + i];
    }
    const int srcl = (l & 32) | 8;         // ones-row sum lives in col 8
#pragma unroll
    for (int r2i = 0; r2i < 16; r2i++) {
      int qr = qbase + (r2i & 3) + 8 * (r2i >> 2) + 4 * hi;
      float ls = __shfl(oa1[r2i], srcl);
      float inv = 1.0f / ls;
      Xo[qr * ND + h * 40 + l31] = f2bru(oa0[r2i] * inv);
      if (l31 < 8) Xo[qr * ND + h * 40 + 32 + l31] = f2bru(oa1[r2i] * inv);
    }
  }
}

// ---------------------------------------------------------------------------
// Kernel 3: out = Xo @ Wo^T + bo. 64x64 tile, BK=64, 5 iters, grid (64, 5)
// = 320 blocks. 4 waves in 2x2 layout, one f32x16 acc each. A/B stride 88
// shorts, aligned b128 ops.
// ---------------------------------------------------------------------------
__global__ __launch_bounds__(256) void proj_out_kernel(
    const unsigned short* __restrict__ Xo, const float* __restrict__ Wo,
    const float* __restrict__ bo, float* __restrict__ out) {
  __shared__ __align__(16) unsigned short As[64 * 88];
  __shared__ __align__(16) unsigned short Bs[64 * 88];
  const int t = threadIdx.x;
  const int w = t >> 6, l = t & 63, l31 = l & 31, hi = l >> 5;
  const int bm = blockIdx.x * 64;
  const int bnn = blockIdx.y * 64;
  const int m0 = (w >> 1) * 32, n0 = (w & 1) * 32;
  f32x16 acc = {0,0,0,0,0,0,0,0,0,0,0,0,0,0,0,0};
  const unsigned short* af = As + (m0 + l31) * 88 + hi * 8;
  const unsigned short* bf = Bs + (n0 + l31) * 88 + hi * 8;
  for (int k0 = 0; k0 < ND; k0 += 64) {
    __syncthreads();
#pragma unroll
    for (int i = 0; i < 2; i++) {            // A: 64 rows x 8 chunks, bf16 src
      int c = t + i * 256;
      int row = c >> 3, kc = (c & 7) << 3;
      uint4 v = *(const uint4*)(Xo + (bm + row) * ND + k0 + kc);
      st16a(As + row * 88 + kc, v);
    }
#pragma unroll
    for (int i = 0; i < 2; i++) {            // B: 64 rows x 8 chunks, fp32 src
      int c = t + i * 256;
      int row = c >> 3, kc = (c & 7) << 3;
      const float* gp = Wo + (bnn + row) * ND + k0 + kc;
      float4 v0 = *(const float4*)gp, v1 = *(const float4*)(gp + 4);
      st16a(Bs + row * 88 + kc,
            make_uint4(pk2ru(v0.x, v0.y), pk2ru(v0.z, v0.w),
                       pk2ru(v1.x, v1.y), pk2ru(v1.z, v1.w)));
    }
    __syncthreads();
#pragma unroll
    for (int ks = 0; ks < 4; ks++) {
      acc = __builtin_amdgcn_mfma_f32_32x32x16_bf16(
          ld8a(af + ks * 16), ld8a(bf + ks * 16), acc, 0, 0, 0);
    }
  }
  const int j = bnn + n0 + l31;
  const float bj = bo[j];
#pragma unroll
  for (int r2 = 0; r2 < 16; r2++) {
    int row = bm + m0 + (r2 & 3) + 8 * (r2 >> 2) + 4 * hi;
    out[row * ND + j] = acc[r2] + bj;
  }
}

extern "C" void kernel_launch(void* const* d_in, const int* in_sizes, int n_in,
                              void* d_out, int out_size, void* d_ws, size_t ws_size,
                              hipStream_t stream) {
  (void)in_sizes; (void)n_in; (void)out_size; (void)ws_size;
  const float* x  = (const float*)d_in[0];
  const float* Wq = (const float*)d_in[1];
  const float* Wk = (const float*)d_in[2];
  const float* Wv = (const float*)d_in[3];
  const float* Wo = (const float*)d_in[4];
  const float* bo = (const float*)d_in[5];
  float* out = (float*)d_out;

  unsigned short* Qp = (unsigned short*)d_ws;   // 8*HS48
  unsigned short* Kp = Qp + 8 * HS48;           // 8*HS48
  unsigned short* Vt = Kp + 8 * HS48;           // 8*VTH
  unsigned short* Xo = Vt + 8 * VTH;            // XN
  // ws use ~11 MB

  proj_qkv_kernel<<<dim3(64, 15), 256, 0, stream>>>(x, Wq, Wk, Wv, Qp, Kp, Vt);
  attn_kernel<<<dim3(256), 512, 0, stream>>>(Qp, Kp, Vt, Xo);
  proj_out_kernel<<<dim3(64, 5), 256, 0, stream>>>(Xo, Wo, bo, out);
}